// Round 1
// baseline (1010.721 us; speedup 1.0000x reference)
//
#include <hip/hip_runtime.h>

namespace {

constexpr int C  = 64;    // input channels
constexpr int H  = 448;   // rows (= conv groups)
constexpr int W  = 608;   // width
constexpr int K  = 32;    // stage-1 classes
constexpr int B  = 2;     // batch
constexpr int TW = 256;   // pixels per block tile
constexpr int NTILE = (W + TW - 1) / TW;  // 3

__device__ __forceinline__ float lrelu(float v) {
    return v >= 0.0f ? v : 0.01f * v;
}

__global__ __launch_bounds__(256, 2)
void reg1stage_kernel(const float* __restrict__ x,
                      const float* __restrict__ W1, const float* __restrict__ b1,
                      const float* __restrict__ W2, const float* __restrict__ b2,
                      const float* __restrict__ W3, const float* __restrict__ b3,
                      const float* __restrict__ Wr, const float* __restrict__ br,
                      float* __restrict__ out)
{
    // Per-thread a1 scratch (column per thread). No cross-thread sharing ->
    // no __syncthreads needed. Bank view: addr = (c*256+tid)*4 -> bank=tid%32,
    // 2 lanes/bank = free (m136).
    __shared__ float A[C][TW];

    const int tid  = threadIdx.x;
    const int blk  = blockIdx.x;          // [0, B*H*NTILE)
    const int tile = blk % NTILE;
    const int bh   = blk / NTILE;
    const int h    = bh % H;
    const int b    = bh / H;
    const int w    = tile * TW + tid;
    if (w >= W) return;                   // no barriers below -> safe early exit

    const size_t HW = (size_t)H * W;
    const float* __restrict__ xcol = x + ((size_t)b * C * H + (size_t)h) * W + w;
    const float* __restrict__ W1h  = W1 + (size_t)h * C * C;
    const float* __restrict__ W2h  = W2 + (size_t)h * C * C;
    const float* __restrict__ W3h  = W3 + (size_t)h * K * C;
    const float* __restrict__ b1h  = b1 + (size_t)h * C;
    const float* __restrict__ b2h  = b2 + (size_t)h * C;
    const float* __restrict__ b3h  = b3 + (size_t)h * K;

    // ---------------- layer 1: a1 = lrelu(W1[h] @ x + b1) ----------------
    float acc[C];
#pragma unroll
    for (int o = 0; o < C; ++o) acc[o] = 0.0f;

    for (int c4 = 0; c4 < C / 4; ++c4) {
        const float xv0 = xcol[(size_t)(4 * c4 + 0) * HW];
        const float xv1 = xcol[(size_t)(4 * c4 + 1) * HW];
        const float xv2 = xcol[(size_t)(4 * c4 + 2) * HW];
        const float xv3 = xcol[(size_t)(4 * c4 + 3) * HW];
#pragma unroll
        for (int o = 0; o < C; ++o) {
            // uniform address -> s_load_dwordx4, FMA consumes SGPR operand
            const float4 wv = *reinterpret_cast<const float4*>(W1h + o * C + 4 * c4);
            acc[o] = fmaf(wv.x, xv0, acc[o]);
            acc[o] = fmaf(wv.y, xv1, acc[o]);
            acc[o] = fmaf(wv.z, xv2, acc[o]);
            acc[o] = fmaf(wv.w, xv3, acc[o]);
        }
    }
#pragma unroll
    for (int o = 0; o < C; ++o) {
        A[o][tid] = lrelu(acc[o] + b1h[o]);
    }

    // ---------------- layer 2: a2 = lrelu(W2[h] @ a1 + b2) ----------------
    float a2[C];
#pragma unroll
    for (int o = 0; o < C; ++o) a2[o] = 0.0f;

    for (int c4 = 0; c4 < C / 4; ++c4) {
        const float xv0 = A[4 * c4 + 0][tid];
        const float xv1 = A[4 * c4 + 1][tid];
        const float xv2 = A[4 * c4 + 2][tid];
        const float xv3 = A[4 * c4 + 3][tid];
#pragma unroll
        for (int o = 0; o < C; ++o) {
            const float4 wv = *reinterpret_cast<const float4*>(W2h + o * C + 4 * c4);
            a2[o] = fmaf(wv.x, xv0, a2[o]);
            a2[o] = fmaf(wv.y, xv1, a2[o]);
            a2[o] = fmaf(wv.z, xv2, a2[o]);
            a2[o] = fmaf(wv.w, xv3, a2[o]);
        }
    }
#pragma unroll
    for (int o = 0; o < C; ++o) a2[o] = lrelu(a2[o] + b2h[o]);

    // ---------------- layer 3 + argmax (lrelu is monotone -> skip it) -----
    float best = -3.402823466e38f;
    int   bi   = 0;
    for (int k = 0; k < K; ++k) {
        float s = b3h[k];
#pragma unroll
        for (int c4 = 0; c4 < C / 4; ++c4) {
            const float4 wv = *reinterpret_cast<const float4*>(W3h + k * C + 4 * c4);
            s = fmaf(wv.x, a2[4 * c4 + 0], s);
            s = fmaf(wv.y, a2[4 * c4 + 1], s);
            s = fmaf(wv.z, a2[4 * c4 + 2], s);
            s = fmaf(wv.w, a2[4 * c4 + 3], s);
        }
        if (s > best) { best = s; bi = k; }   // strict > keeps FIRST max (np semantics)
    }

    // ---------------- conditional regression on original x ----------------
    const int flat = h * K + bi;
    const float4* __restrict__ wr4 =
        reinterpret_cast<const float4*>(Wr + (size_t)flat * C * 2);
    float f0 = 0.0f, f1 = 0.0f;
#pragma unroll 8
    for (int c2 = 0; c2 < C / 2; ++c2) {
        const float4 wv = wr4[c2];   // per-lane gather; 32 rows/h -> L1-hot
        const float xa = xcol[(size_t)(2 * c2 + 0) * HW];
        const float xb = xcol[(size_t)(2 * c2 + 1) * HW];
        f0 = fmaf(xa, wv.x, f0);
        f1 = fmaf(xa, wv.y, f1);
        f0 = fmaf(xb, wv.z, f0);
        f1 = fmaf(xb, wv.w, f1);
    }
    const float r0 = lrelu(f0 + br[2 * flat + 0]);
    const float r1 = lrelu(f1 + br[2 * flat + 1]);
    const float xpos = ((float)flat + r0) * (1.0f / K);
    const float mask = lrelu(r1);            // mask = lrelu(reg[...,1]) -> double lrelu

    const size_t opix = ((size_t)b * H + h) * W + w;
    out[opix] = xpos;
    out[(size_t)B * H * W + opix] = mask;
}

} // namespace

extern "C" void kernel_launch(void* const* d_in, const int* in_sizes, int n_in,
                              void* d_out, int out_size, void* d_ws, size_t ws_size,
                              hipStream_t stream) {
    const float* x  = (const float*)d_in[0];
    const float* W1 = (const float*)d_in[1];
    const float* b1 = (const float*)d_in[2];
    const float* W2 = (const float*)d_in[3];
    const float* b2 = (const float*)d_in[4];
    const float* W3 = (const float*)d_in[5];
    const float* b3 = (const float*)d_in[6];
    const float* Wr = (const float*)d_in[7];
    const float* br = (const float*)d_in[8];
    float* out = (float*)d_out;

    dim3 grid(B * H * NTILE);
    dim3 block(TW);
    hipLaunchKernelGGL(reg1stage_kernel, grid, block, 0, stream,
                       x, W1, b1, W2, b2, W3, b3, Wr, br, out);
}

// Round 4
// 809.086 us; speedup vs baseline: 1.2492x; 1.2492x over previous
//
#include <hip/hip_runtime.h>

namespace {

constexpr int C  = 64;    // input channels
constexpr int H  = 448;   // rows (= conv groups)
constexpr int W  = 608;   // width
constexpr int K  = 32;    // stage-1 classes
constexpr int B  = 2;     // batch
constexpr int TW = 256;   // pixels per block tile
constexpr int NTILE = (W + TW - 1) / TW;  // 3

constexpr size_t W2T_BYTES = (size_t)H * C * C * sizeof(float);  // 14.7 MB

__device__ __forceinline__ float lrelu(float v) {
    return v >= 0.0f ? v : 0.01f * v;
}

// One-shot 64x64 transpose per h: W2T[h][c][o] = W2[h][o][c].
// Padded LDS tile -> conflict-free both directions.
__global__ __launch_bounds__(256)
void transpose_w2(const float* __restrict__ W2, float* __restrict__ W2T) {
    __shared__ float t[C][C + 1];
    const int h = blockIdx.x;
    const float* __restrict__ in  = W2  + (size_t)h * C * C;
    float* __restrict__       op  = W2T + (size_t)h * C * C;
    const int tid = threadIdx.x;
#pragma unroll
    for (int k = 0; k < (C * C) / 256; ++k) {
        const int idx = tid + k * 256;           // coalesced read
        t[idx >> 6][idx & 63] = in[idx];
    }
    __syncthreads();
#pragma unroll
    for (int k = 0; k < (C * C) / 256; ++k) {
        const int idx = tid + k * 256;           // coalesced write
        op[idx] = t[idx & 63][idx >> 6];         // W2T[c][o] = W2[o][c]
    }
}

// Fused pipeline, one pixel per thread, zero LDS, zero barriers.
// c-outer fusion of layers 1+2: a1_c is a scalar, no a1[] array, all
// register-array indices are compile-time constants (no scratch spills).
template <bool USE_WT>
__global__ __launch_bounds__(256, 3)
void reg1stage_kernel(const float* __restrict__ x,
                      const float* __restrict__ W1, const float* __restrict__ b1,
                      const float* __restrict__ W2orT, const float* __restrict__ b2,
                      const float* __restrict__ W3, const float* __restrict__ b3,
                      const float* __restrict__ Wr, const float* __restrict__ br,
                      float* __restrict__ out)
{
    const int tid  = threadIdx.x;
    const int blk  = blockIdx.x;          // [0, B*H*NTILE)
    const int tile = blk % NTILE;
    const int bh   = blk / NTILE;
    const int h    = bh % H;
    const int b    = bh / H;
    const int w    = tile * TW + tid;
    if (w >= W) return;                   // no barriers anywhere -> safe

    const size_t HW = (size_t)H * W;
    const float* __restrict__ xcol = x + ((size_t)b * C * H + (size_t)h) * W + w;
    const float* __restrict__ W1h  = W1    + (size_t)h * C * C;
    const float* __restrict__ W2h  = W2orT + (size_t)h * C * C;
    const float* __restrict__ W3h  = W3    + (size_t)h * K * C;
    const float* __restrict__ b1h  = b1 + (size_t)h * C;
    const float* __restrict__ b2h  = b2 + (size_t)h * C;
    const float* __restrict__ b3h  = b3 + (size_t)h * K;

    // ---- x loaded from HBM exactly once; stays in registers to the end ----
    float xv[C];
#pragma unroll
    for (int c = 0; c < C; ++c) xv[c] = xcol[(size_t)c * HW];

    // ---- a2 accumulators seeded with b2 ----
    float a2[C];
#pragma unroll
    for (int o = 0; o < C; ++o) a2[o] = b2h[o];

    // ---- fused layers 1+2, c-outer; a1_c is a scalar ----
#pragma unroll 1
    for (int c = 0; c < C; ++c) {
        // a1_c = lrelu(b1[c] + W1[c,:] . x)   (4 partial chains for ILP)
        float p0 = 0.0f, p1 = 0.0f, p2 = 0.0f, p3 = 0.0f;
#pragma unroll
        for (int i = 0; i < C / 4; ++i) {
            const float4 wv = *reinterpret_cast<const float4*>(W1h + c * C + 4 * i);
            p0 = fmaf(wv.x, xv[4 * i + 0], p0);
            p1 = fmaf(wv.y, xv[4 * i + 1], p1);
            p2 = fmaf(wv.z, xv[4 * i + 2], p2);
            p3 = fmaf(wv.w, xv[4 * i + 3], p3);
        }
        const float a1c = lrelu(b1h[c] + ((p0 + p1) + (p2 + p3)));

        // a2[o] += W2T[c][o] * a1c  (all 64 updates independent)
        if constexpr (USE_WT) {
#pragma unroll
            for (int i = 0; i < C / 4; ++i) {
                const float4 wv = *reinterpret_cast<const float4*>(W2h + c * C + 4 * i);
                a2[4 * i + 0] = fmaf(wv.x, a1c, a2[4 * i + 0]);
                a2[4 * i + 1] = fmaf(wv.y, a1c, a2[4 * i + 1]);
                a2[4 * i + 2] = fmaf(wv.z, a1c, a2[4 * i + 2]);
                a2[4 * i + 3] = fmaf(wv.w, a1c, a2[4 * i + 3]);
            }
        } else {
            // fallback: column access on untransposed W2 (uniform scalar loads)
#pragma unroll
            for (int o = 0; o < C; ++o)
                a2[o] = fmaf(W2h[o * C + c], a1c, a2[o]);
        }
    }
#pragma unroll
    for (int o = 0; o < C; ++o) a2[o] = lrelu(a2[o]);

    // ---- layer 3 + argmax, k-outer tiles of 8, no cls array ----
    // lrelu is strictly monotone -> argmax over pre-activation + bias.
    float best = -3.402823466e38f;
    int   bi   = 0;
#pragma unroll 1
    for (int kt = 0; kt < K / 8; ++kt) {
        float s[8];
#pragma unroll
        for (int j = 0; j < 8; ++j) s[j] = b3h[kt * 8 + j];
#pragma unroll
        for (int i = 0; i < C / 4; ++i) {
#pragma unroll
            for (int j = 0; j < 8; ++j) {
                const float4 wv =
                    *reinterpret_cast<const float4*>(W3h + (kt * 8 + j) * C + 4 * i);
                s[j] = fmaf(wv.x, a2[4 * i + 0], s[j]);
                s[j] = fmaf(wv.y, a2[4 * i + 1], s[j]);
                s[j] = fmaf(wv.z, a2[4 * i + 2], s[j]);
                s[j] = fmaf(wv.w, a2[4 * i + 3], s[j]);
            }
        }
#pragma unroll
        for (int j = 0; j < 8; ++j) {
            if (s[j] > best) { best = s[j]; bi = kt * 8 + j; }  // strict > = first max
        }
    }

    // ---- conditional regression straight from register-resident x ----
    const int flat = h * K + bi;
    const float4* __restrict__ wr4 =
        reinterpret_cast<const float4*>(Wr + (size_t)flat * C * 2);
    float f0 = 0.0f, f1 = 0.0f;
#pragma unroll
    for (int c2 = 0; c2 < C / 2; ++c2) {
        const float4 wv = wr4[c2];   // per-lane gather; 32 rows/h -> L1-hot
        f0 = fmaf(xv[2 * c2 + 0], wv.x, f0);
        f1 = fmaf(xv[2 * c2 + 0], wv.y, f1);
        f0 = fmaf(xv[2 * c2 + 1], wv.z, f0);
        f1 = fmaf(xv[2 * c2 + 1], wv.w, f1);
    }
    const float r0 = lrelu(f0 + br[2 * flat + 0]);
    const float r1 = lrelu(f1 + br[2 * flat + 1]);
    const float xpos = ((float)flat + r0) * (1.0f / K);
    const float mask = lrelu(r1);            // double lrelu, per reference

    const size_t opix = ((size_t)b * H + h) * W + w;
    out[opix] = xpos;
    out[(size_t)B * H * W + opix] = mask;
}

} // namespace

extern "C" void kernel_launch(void* const* d_in, const int* in_sizes, int n_in,
                              void* d_out, int out_size, void* d_ws, size_t ws_size,
                              hipStream_t stream) {
    const float* x  = (const float*)d_in[0];
    const float* W1 = (const float*)d_in[1];
    const float* b1 = (const float*)d_in[2];
    const float* W2 = (const float*)d_in[3];
    const float* b2 = (const float*)d_in[4];
    const float* W3 = (const float*)d_in[5];
    const float* b3 = (const float*)d_in[6];
    const float* Wr = (const float*)d_in[7];
    const float* br = (const float*)d_in[8];
    float* out = (float*)d_out;

    dim3 grid(B * H * NTILE);
    dim3 block(TW);

    if (ws_size >= W2T_BYTES) {
        float* W2T = (float*)d_ws;
        hipLaunchKernelGGL(transpose_w2, dim3(H), dim3(256), 0, stream, W2, W2T);
        hipLaunchKernelGGL((reg1stage_kernel<true>), grid, block, 0, stream,
                           x, W1, b1, W2T, b2, W3, b3, Wr, br, out);
    } else {
        hipLaunchKernelGGL((reg1stage_kernel<false>), grid, block, 0, stream,
                           x, W1, b1, W2, b2, W3, b3, Wr, br, out);
    }
}

// Round 5
// 446.593 us; speedup vs baseline: 2.2632x; 1.8117x over previous
//
#include <hip/hip_runtime.h>

namespace {

constexpr int C  = 64;    // input channels
constexpr int H  = 448;   // rows (= conv groups)
constexpr int Wd = 608;   // width
constexpr int K  = 32;    // stage-1 classes
constexpr int B  = 2;     // batch
constexpr int TW = 256;   // pixels per block tile
constexpr int NTILE = 3;             // ceil(608/256)
constexpr int NBLK  = B * H * NTILE; // 2688, % 8 == 0 -> bijective XCD swizzle

constexpr size_t W2T_BYTES = (size_t)H * C * C * sizeof(float);  // 14.7 MB

__device__ __forceinline__ float lrelu(float v) {
    return v >= 0.0f ? v : 0.01f * v;
}

// One-shot 64x64 transpose per h: W2T[h][c][o] = W2[h][o][c].
__global__ __launch_bounds__(256)
void transpose_w2(const float* __restrict__ W2, float* __restrict__ W2T) {
    __shared__ float t[C][C + 1];
    const int h = blockIdx.x;
    const float* __restrict__ in  = W2  + (size_t)h * C * C;
    float* __restrict__       op  = W2T + (size_t)h * C * C;
    const int tid = threadIdx.x;
#pragma unroll
    for (int k = 0; k < (C * C) / 256; ++k) {
        const int idx = tid + k * 256;
        t[idx >> 6][idx & 63] = in[idx];
    }
    __syncthreads();
#pragma unroll
    for (int k = 0; k < (C * C) / 256; ++k) {
        const int idx = tid + k * 256;
        op[idx] = t[idx & 63][idx >> 6];
    }
}

// Fused pipeline, one pixel per thread. Weights staged in LDS once per
// block; all weight reads are wave-uniform ds_read_b128 (broadcast,
// conflict-free, pipelined in VGPRs) instead of SGPR-starved s_loads.
template <bool USE_WT>
__global__ __launch_bounds__(256, 3)
void reg1stage_kernel(const float* __restrict__ x,
                      const float* __restrict__ W1, const float* __restrict__ b1,
                      const float* __restrict__ W2orT, const float* __restrict__ b2,
                      const float* __restrict__ W3, const float* __restrict__ b3,
                      const float* __restrict__ Wr, const float* __restrict__ br,
                      float* __restrict__ out)
{
    __shared__ float sW1[C * C];   // 16 KB
    __shared__ float sW2[C * C];   // 16 KB (transposed if USE_WT)
    __shared__ float sW3[K * C];   //  8 KB
    __shared__ float sB1[C];
    __shared__ float sB3[K];

    const int tid = threadIdx.x;

    // XCD-aware swizzle: consecutive h on one XCD -> per-XCD weight
    // footprint 56 h x ~57 KB = 3.2 MB < 4 MB L2. Bijective (2688 % 8 == 0).
    const int wg  = blockIdx.x;
    const int swz = (wg & 7) * (NBLK / 8) + (wg >> 3);
    const int h    = swz / 6;            // 6 blocks per h: 2 batches x 3 tiles
    const int rem  = swz - 6 * h;
    const int b    = rem / 3;
    const int tile = rem - 3 * (rem / 3);
    const int w    = tile * TW + tid;
    const bool valid = (w < Wd);
    const int wc   = valid ? w : (Wd - 1);   // clamp; no early return (barrier)

    const size_t HW = (size_t)H * Wd;
    const float* __restrict__ xcol = x + ((size_t)b * C * H + (size_t)h) * Wd + wc;
    const float* __restrict__ W1h  = W1    + (size_t)h * C * C;
    const float* __restrict__ W2h  = W2orT + (size_t)h * C * C;
    const float* __restrict__ W3h  = W3    + (size_t)h * K * C;
    const float* __restrict__ b1h  = b1 + (size_t)h * C;
    const float* __restrict__ b2h  = b2 + (size_t)h * C;
    const float* __restrict__ b3h  = b3 + (size_t)h * K;

    // ---- stage weights: coalesced float4 copies (one-time, L2-hot) ----
    {
        const float4* __restrict__ g1 = reinterpret_cast<const float4*>(W1h);
        const float4* __restrict__ g2 = reinterpret_cast<const float4*>(W2h);
        const float4* __restrict__ g3 = reinterpret_cast<const float4*>(W3h);
        float4* s1 = reinterpret_cast<float4*>(sW1);
        float4* s2 = reinterpret_cast<float4*>(sW2);
        float4* s3 = reinterpret_cast<float4*>(sW3);
#pragma unroll
        for (int r = 0; r < 4; ++r) s1[tid + 256 * r] = g1[tid + 256 * r];
#pragma unroll
        for (int r = 0; r < 4; ++r) s2[tid + 256 * r] = g2[tid + 256 * r];
#pragma unroll
        for (int r = 0; r < 2; ++r) s3[tid + 256 * r] = g3[tid + 256 * r];
        if (tid < C) sB1[tid] = b1h[tid];
        else if (tid >= 64 && tid < 64 + K) sB3[tid - 64] = b3h[tid - 64];
    }

    // ---- x loaded from HBM exactly once; stays in registers ----
    float xv[C];
#pragma unroll
    for (int c = 0; c < C; ++c) xv[c] = xcol[(size_t)c * HW];

    // ---- a2 accumulators seeded with b2 (one-time scalar loads) ----
    float a2[C];
#pragma unroll
    for (int o = 0; o < C; ++o) a2[o] = b2h[o];

    __syncthreads();   // staging complete

    // ---- fused layers 1+2, c-outer; a1_c is a scalar ----
#pragma unroll 1
    for (int c = 0; c < C; ++c) {
        float p0 = 0.0f, p1 = 0.0f, p2 = 0.0f, p3 = 0.0f;
#pragma unroll
        for (int i = 0; i < C / 4; ++i) {
            const float4 wv = *reinterpret_cast<const float4*>(&sW1[c * C + 4 * i]);
            p0 = fmaf(wv.x, xv[4 * i + 0], p0);
            p1 = fmaf(wv.y, xv[4 * i + 1], p1);
            p2 = fmaf(wv.z, xv[4 * i + 2], p2);
            p3 = fmaf(wv.w, xv[4 * i + 3], p3);
        }
        const float a1c = lrelu(sB1[c] + ((p0 + p1) + (p2 + p3)));

        if constexpr (USE_WT) {
            // a2[o] += W2T[c][o] * a1c  (64 independent updates)
#pragma unroll
            for (int i = 0; i < C / 4; ++i) {
                const float4 wv = *reinterpret_cast<const float4*>(&sW2[c * C + 4 * i]);
                a2[4 * i + 0] = fmaf(wv.x, a1c, a2[4 * i + 0]);
                a2[4 * i + 1] = fmaf(wv.y, a1c, a2[4 * i + 1]);
                a2[4 * i + 2] = fmaf(wv.z, a1c, a2[4 * i + 2]);
                a2[4 * i + 3] = fmaf(wv.w, a1c, a2[4 * i + 3]);
            }
        } else {
            // fallback: column reads on untransposed W2 (uniform b32 broadcasts)
#pragma unroll
            for (int o = 0; o < C; ++o)
                a2[o] = fmaf(sW2[o * C + c], a1c, a2[o]);
        }
    }
#pragma unroll
    for (int o = 0; o < C; ++o) a2[o] = lrelu(a2[o]);

    // ---- layer 3 + argmax, k-tiles of 8 (lrelu monotone -> skip it) ----
    float best = -3.402823466e38f;
    int   bi   = 0;
#pragma unroll 1
    for (int kt = 0; kt < K / 8; ++kt) {
        float s[8];
#pragma unroll
        for (int j = 0; j < 8; ++j) s[j] = sB3[kt * 8 + j];
#pragma unroll
        for (int i = 0; i < C / 4; ++i) {
#pragma unroll
            for (int j = 0; j < 8; ++j) {
                const float4 wv =
                    *reinterpret_cast<const float4*>(&sW3[(kt * 8 + j) * C + 4 * i]);
                s[j] = fmaf(wv.x, a2[4 * i + 0], s[j]);
                s[j] = fmaf(wv.y, a2[4 * i + 1], s[j]);
                s[j] = fmaf(wv.z, a2[4 * i + 2], s[j]);
                s[j] = fmaf(wv.w, a2[4 * i + 3], s[j]);
            }
        }
#pragma unroll
        for (int j = 0; j < 8; ++j) {
            if (s[j] > best) { best = s[j]; bi = kt * 8 + j; }  // first max
        }
    }

    // ---- conditional regression straight from register-resident x ----
    const int flat = h * K + bi;
    const float4* __restrict__ wr4 =
        reinterpret_cast<const float4*>(Wr + (size_t)flat * C * 2);
    float f0 = 0.0f, f1 = 0.0f;
#pragma unroll
    for (int c2 = 0; c2 < C / 2; ++c2) {
        const float4 wv = wr4[c2];   // per-lane gather; L2-hot after swizzle
        f0 = fmaf(xv[2 * c2 + 0], wv.x, f0);
        f1 = fmaf(xv[2 * c2 + 0], wv.y, f1);
        f0 = fmaf(xv[2 * c2 + 1], wv.z, f0);
        f1 = fmaf(xv[2 * c2 + 1], wv.w, f1);
    }
    const float r0 = lrelu(f0 + br[2 * flat + 0]);
    const float r1 = lrelu(f1 + br[2 * flat + 1]);
    const float xpos = ((float)flat + r0) * (1.0f / K);
    const float mask = lrelu(r1);

    if (valid) {
        const size_t opix = ((size_t)b * H + h) * Wd + w;
        out[opix] = xpos;
        out[(size_t)B * H * Wd + opix] = mask;
    }
}

} // namespace

extern "C" void kernel_launch(void* const* d_in, const int* in_sizes, int n_in,
                              void* d_out, int out_size, void* d_ws, size_t ws_size,
                              hipStream_t stream) {
    const float* x  = (const float*)d_in[0];
    const float* W1 = (const float*)d_in[1];
    const float* b1 = (const float*)d_in[2];
    const float* W2 = (const float*)d_in[3];
    const float* b2 = (const float*)d_in[4];
    const float* W3 = (const float*)d_in[5];
    const float* b3 = (const float*)d_in[6];
    const float* Wr = (const float*)d_in[7];
    const float* br = (const float*)d_in[8];
    float* out = (float*)d_out;

    dim3 grid(NBLK);
    dim3 block(TW);

    if (ws_size >= W2T_BYTES) {
        float* W2T = (float*)d_ws;
        hipLaunchKernelGGL(transpose_w2, dim3(H), dim3(256), 0, stream, W2, W2T);
        hipLaunchKernelGGL((reg1stage_kernel<true>), grid, block, 0, stream,
                           x, W1, b1, W2T, b2, W3, b3, Wr, br, out);
    } else {
        hipLaunchKernelGGL((reg1stage_kernel<false>), grid, block, 0, stream,
                           x, W1, b1, W2, b2, W3, b3, Wr, br, out);
    }
}